// Round 1
// baseline (525.572 us; speedup 1.0000x reference)
//
#include <hip/hip_runtime.h>
#include <math.h>

#define EPS 1e-8f

__device__ __forceinline__ float wave_reduce_sum(float v) {
#pragma unroll
  for (int off = 32; off > 0; off >>= 1)
    v += __shfl_xor(v, off, 64);
  return v;
}

__device__ __forceinline__ float wave_reduce_max(float v) {
#pragma unroll
  for (int off = 32; off > 0; off >>= 1)
    v = fmaxf(v, __shfl_xor(v, off, 64));
  return v;
}

// One wave per node: compute L2 norm, store it, and initialize agg with the
// self-loop contribution (mask = self-cosine-sim > 0.5, computed exactly per
// the reference formula).
template <int D>
__global__ __launch_bounds__(256) void node_norm_init(
    const float* __restrict__ x, float* __restrict__ norms,
    float* __restrict__ agg, int N) {
  constexpr int V = D / 64;  // floats per lane
  int node = (int)((blockIdx.x * blockDim.x + threadIdx.x) >> 6);
  int lane = threadIdx.x & 63;
  if (node >= N) return;
  const float* row = x + (size_t)node * D + lane * V;
  float v[V];
  if constexpr (V == 2) {
    float2 t = *(const float2*)row;
    v[0] = t.x; v[1] = t.y;
  } else {
    float4 t = *(const float4*)row;
    v[0] = t.x; v[1] = t.y; v[2] = t.z; v[3] = t.w;
  }
  float ss = 0.f;
#pragma unroll
  for (int q = 0; q < V; ++q) ss += v[q] * v[q];
  ss = wave_reduce_sum(ss);
  if (lane == 0) norms[node] = sqrtf(ss);
  // self-loop: dot = ss, denom = max(norm^2, eps); sim>0.5 <=> dot>0.5*denom
  bool pass = ss > 0.5f * fmaxf(ss, EPS);
  float* arow = agg + (size_t)node * D + lane * V;
#pragma unroll
  for (int q = 0; q < V; ++q) arow[q] = pass ? v[q] : 0.f;
}

// One wave per edge: cosine-sim gate + atomic scatter-add of the source row.
template <int D>
__global__ __launch_bounds__(256) void edge_conv(
    const float* __restrict__ feat, const float* __restrict__ norms,
    const int* __restrict__ src, const int* __restrict__ dst,
    float* __restrict__ agg, int E) {
  constexpr int V = D / 64;
  int e = (int)((blockIdx.x * blockDim.x + threadIdx.x) >> 6);
  int lane = threadIdx.x & 63;
  if (e >= E) return;
  int s = src[e];
  int d = dst[e];
  const float* srow = feat + (size_t)s * D + lane * V;
  const float* drow = feat + (size_t)d * D + lane * V;
  float sv[V], dv[V];
  if constexpr (V == 2) {
    float2 a = *(const float2*)srow;
    float2 b = *(const float2*)drow;
    sv[0] = a.x; sv[1] = a.y;
    dv[0] = b.x; dv[1] = b.y;
  } else {
    float4 a = *(const float4*)srow;
    float4 b = *(const float4*)drow;
    sv[0] = a.x; sv[1] = a.y; sv[2] = a.z; sv[3] = a.w;
    dv[0] = b.x; dv[1] = b.y; dv[2] = b.z; dv[3] = b.w;
  }
  float dot = 0.f;
#pragma unroll
  for (int q = 0; q < V; ++q) dot += sv[q] * dv[q];
  dot = wave_reduce_sum(dot);  // all lanes hold full sum -> uniform branch
  float denom = fmaxf(norms[s] * norms[d], EPS);
  if (dot > 0.5f * denom) {
    float* arow = agg + (size_t)d * D + lane * V;
#pragma unroll
    for (int q = 0; q < V; ++q) atomicAdd(&arow[q], sv[q]);
  }
}

// C[M,N] = act(A[M,K] @ W[N,K]^T + bias), 64x64 block tile, 4x4 per thread.
template <int BK, bool RELU>
__global__ __launch_bounds__(256) void gemm_bias(
    const float* __restrict__ A, const float* __restrict__ W,
    const float* __restrict__ bias, float* __restrict__ C,
    int M, int N, int K) {
  __shared__ float As[BK][68];  // As[k][m]; pad 68 keeps float4 alignment
  __shared__ float Bs[BK][68];  // Bs[k][n] = W[n][k]
  const int tid = threadIdx.x;
  const int m0 = blockIdx.x * 64;
  const int n0 = blockIdx.y * 64;
  const int mv = tid >> 3;        // 0..31
  const int kv = (tid & 7) * 4;   // 0,4,..,28
  float acc[4][4] = {};
  for (int k0 = 0; k0 < K; k0 += BK) {
#pragma unroll
    for (int i = 0; i < 2; ++i) {
      int r = mv + i * 32;  // row within tile, also reused as col for B
      int gm = m0 + r;
      float4 a = (gm < M) ? *(const float4*)&A[(size_t)gm * K + k0 + kv]
                          : make_float4(0.f, 0.f, 0.f, 0.f);
      As[kv + 0][r] = a.x; As[kv + 1][r] = a.y;
      As[kv + 2][r] = a.z; As[kv + 3][r] = a.w;
      // N is a multiple of 64 here (256 or 64): no guard needed
      float4 b = *(const float4*)&W[(size_t)(n0 + r) * K + k0 + kv];
      Bs[kv + 0][r] = b.x; Bs[kv + 1][r] = b.y;
      Bs[kv + 2][r] = b.z; Bs[kv + 3][r] = b.w;
    }
    __syncthreads();
    const int ms = (tid & 15) * 4;
    const int ns = (tid >> 4) * 4;
#pragma unroll
    for (int kk = 0; kk < BK; ++kk) {
      float4 a4 = *(const float4*)&As[kk][ms];
      float4 b4 = *(const float4*)&Bs[kk][ns];
      float av[4] = {a4.x, a4.y, a4.z, a4.w};
      float bv[4] = {b4.x, b4.y, b4.z, b4.w};
#pragma unroll
      for (int i = 0; i < 4; ++i)
#pragma unroll
        for (int j = 0; j < 4; ++j) acc[i][j] += av[i] * bv[j];
    }
    __syncthreads();
  }
  const int ms = (tid & 15) * 4;
  const int ns = (tid >> 4) * 4;
  float4 bb = *(const float4*)&bias[n0 + ns];
  float bv[4] = {bb.x, bb.y, bb.z, bb.w};
#pragma unroll
  for (int i = 0; i < 4; ++i) {
    int gm = m0 + ms + i;
    if (gm < M) {
      float4 o;
      float t0 = acc[i][0] + bv[0];
      float t1 = acc[i][1] + bv[1];
      float t2 = acc[i][2] + bv[2];
      float t3 = acc[i][3] + bv[3];
      if (RELU) {
        t0 = fmaxf(t0, 0.f); t1 = fmaxf(t1, 0.f);
        t2 = fmaxf(t2, 0.f); t3 = fmaxf(t3, 0.f);
      }
      o.x = t0; o.y = t1; o.z = t2; o.w = t3;
      *(float4*)&C[(size_t)gm * N + n0 + ns] = o;
    }
  }
}

// One wave per row of 64 logits: in-place log_softmax.
__global__ __launch_bounds__(256) void log_softmax64(float* __restrict__ out,
                                                     int N) {
  int row = (int)((blockIdx.x * blockDim.x + threadIdx.x) >> 6);
  int lane = threadIdx.x & 63;
  if (row >= N) return;
  float v = out[(size_t)row * 64 + lane];
  float mx = wave_reduce_max(v);
  float e = expf(v - mx);
  float s = wave_reduce_sum(e);
  out[(size_t)row * 64 + lane] = v - mx - logf(s);
}

extern "C" void kernel_launch(void* const* d_in, const int* in_sizes, int n_in,
                              void* d_out, int out_size, void* d_ws,
                              size_t ws_size, hipStream_t stream) {
  const float* x  = (const float*)d_in[0];
  const int* eidx = (const int*)d_in[1];  // harness converts ints to int32
  const float* W1 = (const float*)d_in[2];
  const float* b1 = (const float*)d_in[3];
  const float* W2 = (const float*)d_in[4];
  const float* b2 = (const float*)d_in[5];
  float* out = (float*)d_out;

  const int N = in_sizes[0] / 128;  // 50000
  const int E = in_sizes[1] / 2;    // 800000
  const int* src = eidx;            // edge_index[0]
  const int* dst = eidx + E;        // edge_index[1]

  // workspace layout (floats): h[N*256] | agg[N*256] | norms_x[N] | norms_h[N]
  float* h     = (float*)d_ws;
  float* agg   = h + (size_t)N * 256;
  float* norms = agg + (size_t)N * 256;
  float* normh = norms + N;

  // ---- layer 1 (D=128) ----
  node_norm_init<128><<<(N + 3) / 4, 256, 0, stream>>>(x, norms, agg, N);
  edge_conv<128><<<(E + 3) / 4, 256, 0, stream>>>(x, norms, src, dst, agg, E);
  gemm_bias<32, true><<<dim3((N + 63) / 64, 4), 256, 0, stream>>>(
      agg, W1, b1, h, N, 256, 128);

  // ---- layer 2 (D=256) ----
  node_norm_init<256><<<(N + 3) / 4, 256, 0, stream>>>(h, normh, agg, N);
  edge_conv<256><<<(E + 3) / 4, 256, 0, stream>>>(h, normh, src, dst, agg, E);
  gemm_bias<32, false><<<dim3((N + 63) / 64, 1), 256, 0, stream>>>(
      agg, W2, b2, out, N, 64, 256);

  log_softmax64<<<(N + 3) / 4, 256, 0, stream>>>(out, N);
}